// Round 19
// baseline (864.257 us; speedup 1.0000x reference)
//
#include <hip/hip_runtime.h>

using u16 = unsigned short;
typedef u16 u16x8 __attribute__((ext_vector_type(8)));
typedef __bf16 bf16x8 __attribute__((ext_vector_type(8)));
typedef float f32x4 __attribute__((ext_vector_type(4)));

__device__ __forceinline__ u16 f2bf(float f) {
  unsigned u = __builtin_bit_cast(unsigned, f);
  u += 0x7fffu + ((u >> 16) & 1u);
  return (u16)(u >> 16);
}
__device__ __forceinline__ float bf2f(u16 h) {
  unsigned u = ((unsigned)h) << 16;
  return __builtin_bit_cast(float, u);
}
__device__ __forceinline__ f32x4 mfma16(u16x8 a, u16x8 b, f32x4 c) {
  return __builtin_amdgcn_mfma_f32_16x16x32_bf16(
      __builtin_bit_cast(bf16x8, a), __builtin_bit_cast(bf16x8, b), c, 0, 0, 0);
}
__device__ __forceinline__ float gelu_f(float v) {
  return 0.5f * v * (1.0f + erff(v * 0.70710678118654752f));
}
// async global->LDS, 16B per lane; lds dest = base + lane*16 (wave-uniform base)
__device__ __forceinline__ void gll16(const u16* g, u16* l) {
  __builtin_amdgcn_global_load_lds(
      (const __attribute__((address_space(1))) unsigned*)g,
      (__attribute__((address_space(3))) unsigned*)l, 16, 0, 0);
}

// ---------------- unified weight prep: casts + transposes in ONE launch -----
__global__ __launch_bounds__(256) void prep_kernel(
    const float* __restrict__ Qw, const float* __restrict__ Kw,
    const float* __restrict__ Wp, const float* __restrict__ W1,
    const float* __restrict__ W2, u16* __restrict__ Qc, u16* __restrict__ Kc,
    u16* __restrict__ Wpt, u16* __restrict__ W1t, u16* __restrict__ W2t,
    float qscale) {
  const int bid = blockIdx.x;
  const int tid = threadIdx.x;
  if (bid < 4096) {  // flat vectorized casts
    const float* in = (bid < 2048) ? Qw : Kw;
    u16* outp = (bid < 2048) ? Qc : Kc;
    const float sc = (bid < 2048) ? qscale : 1.0f;
    const size_t i = ((size_t)(bid & 2047) * 256 + tid) * 4;
    float4 v = *(const float4*)(in + i);
    outp[i] = f2bf(v.x * sc);
    outp[i + 1] = f2bf(v.y * sc);
    outp[i + 2] = f2bf(v.z * sc);
    outp[i + 3] = f2bf(v.w * sc);
    return;
  }
  __shared__ float tile[32][33];
  const float* in;
  u16* outp;
  int R, C, t;
  if (bid < 6144)      { in = Wp; outp = Wpt; R = 4096; C = 512;  t = bid - 4096; }
  else if (bid < 7168) { in = W1; outp = W1t; R = 512;  C = 2048; t = bid - 6144; }
  else                 { in = W2; outp = W2t; R = 2048; C = 512;  t = bid - 7168; }
  const int tilesX = C >> 5;
  const int cx = (t % tilesX) * 32, ry = (t / tilesX) * 32;
  const int tx = tid & 31, ty = tid >> 5;
#pragma unroll
  for (int i = 0; i < 32; i += 8)
    tile[ty + i][tx] = in[(size_t)(ry + ty + i) * C + (cx + tx)];
  __syncthreads();
#pragma unroll
  for (int i = 0; i < 32; i += 8)
    outp[(size_t)(cx + ty + i) * R + (ry + tx)] = f2bf(tile[tx][ty + i]);
}

// ---------------- layernorm (D=512); optional split-K sum input; optional
// fused V-tiling output (xnTt chunk-major scatter) ---------------------------
__global__ __launch_bounds__(256) void ln_kernel(
    const float* __restrict__ x, const float* __restrict__ x2,
    const float* __restrict__ g, const float* __restrict__ b,
    u16* __restrict__ obf, u16* __restrict__ vt) {
  const int D = 512;
  int row = blockIdx.x;
  const float* xr = x + (size_t)row * D;
  float2 v = ((const float2*)xr)[threadIdx.x];
  if (x2 != nullptr) {
    float2 v2 = ((const float2*)(x2 + (size_t)row * D))[threadIdx.x];
    v.x += v2.x;
    v.y += v2.y;
  }
  float s = v.x + v.y;
#pragma unroll
  for (int o = 1; o < 64; o <<= 1) s += __shfl_xor(s, o);
  __shared__ float red[4];
  int wid = threadIdx.x >> 6;
  if ((threadIdx.x & 63) == 0) red[wid] = s;
  __syncthreads();
  float mean = (red[0] + red[1] + red[2] + red[3]) * (1.0f / D);
  float dx = v.x - mean, dy = v.y - mean;
  float q = dx * dx + dy * dy;
#pragma unroll
  for (int o = 1; o < 64; o <<= 1) q += __shfl_xor(q, o);
  __syncthreads();
  if ((threadIdx.x & 63) == 0) red[wid] = q;
  __syncthreads();
  float var = (red[0] + red[1] + red[2] + red[3]) * (1.0f / D);
  float rstd = rsqrtf(var + 1e-6f);
  int c = threadIdx.x * 2;
  u16 h0 = f2bf(dx * rstd * g[c] + b[c]);
  u16 h1 = f2bf(dy * rstd * g[c + 1] + b[c + 1]);
  obf[(size_t)row * D + c] = h0;
  obf[(size_t)row * D + c + 1] = h1;
  if (vt != nullptr) {
    // xnTt layout: [b][64][4][512][8]; element (d,t): tile t>>5, chunk (t&31)>>3,
    // pos chunk*4096 + d*8 + (t&7)
    const int bb = row >> 11, t = row & 2047;
    u16* vbase = vt + ((size_t)(bb * 64 + (t >> 5)) * 16384) +
                 (size_t)(((t & 31) >> 3) * 4096) + (t & 7);
    vbase[(size_t)c * 8] = h0;
    vbase[(size_t)(c + 1) * 8] = h1;
  }
}

// ---------------- bf16 GEMM v3: C[M,N] = A[M,K] * Bt[N,K]^T ------------------
// m97 pattern: global_load_lds width-16 staging, BK=64, both-sides XOR swizzle.
// ldB = physical row stride of Bt. bias applied only on z==0.
// mode 0: bf16 out           mode 1: fp32 out, +bias
// mode 2: bf16 out, gelu(+bias)   mode 4: fp32 out, gelu(+bias)+bf16-resid
__global__ __launch_bounds__(256) void gemm_kernel(
    const u16* __restrict__ A, const u16* __restrict__ Bt,
    const float* __restrict__ bias, const void* __restrict__ resid,
    void* __restrict__ Cout, int M, int N, int K, int ldB, int mode,
    size_t sA, size_t sB, size_t sC, size_t aHS) {
  __shared__ u16 As[128 * 64];
  __shared__ u16 Bs[128 * 64];
  A += (size_t)blockIdx.z * sA;
  Bt += (size_t)blockIdx.z * sB;
  const size_t zC = (size_t)blockIdx.z * sC;
  const int m0 = blockIdx.y * 128, n0 = blockIdx.x * 128;
  const int tid = threadIdx.x;
  const int l = tid & 63, wv = tid >> 6;
  const int wr = (wv >> 1) * 64, wc = (wv & 1) * 64;
  const int lr = l & 15, lq = l >> 4;
  const int srow = l >> 3;   // row-in-group 0..7
  const int sc = l & 7;      // chunk 0..7
  f32x4 z4 = {0.f, 0.f, 0.f, 0.f};
  f32x4 acc[4][4];
#pragma unroll
  for (int mi = 0; mi < 4; mi++)
#pragma unroll
    for (int ni = 0; ni < 4; ni++) acc[mi][ni] = z4;

  for (int k0 = 0; k0 < K; k0 += 64) {
    __syncthreads();
#pragma unroll
    for (int j = 0; j < 4; ++j) {
      const int r = wv * 32 + j * 8 + srow;
      const int kc = (sc ^ (r & 7)) * 8;  // pre-swizzled source chunk
      const u16* asrc;
      if (aHS) asrc = A + (size_t)(k0 >> 9) * aHS + (size_t)(m0 + r) * 512 + ((k0 & 511) + kc);
      else asrc = A + (size_t)(m0 + r) * K + k0 + kc;
      gll16(asrc, &As[(wv * 32 + j * 8) * 64]);
      const u16* bsrc = Bt + (size_t)(n0 + r) * ldB + k0 + kc;
      gll16(bsrc, &Bs[(wv * 32 + j * 8) * 64]);
    }
    asm volatile("s_waitcnt vmcnt(0)" ::: "memory");
    __syncthreads();
#pragma unroll
    for (int kk = 0; kk < 2; ++kk) {
      const int rc = ((kk * 4 + lq) ^ (lr & 7)) * 8;  // swizzled read chunk
      u16x8 af[4], bfr[4];
#pragma unroll
      for (int mi = 0; mi < 4; mi++) af[mi] = *(const u16x8*)&As[(wr + mi * 16 + lr) * 64 + rc];
#pragma unroll
      for (int ni = 0; ni < 4; ni++) bfr[ni] = *(const u16x8*)&Bs[(wc + ni * 16 + lr) * 64 + rc];
#pragma unroll
      for (int mi = 0; mi < 4; mi++)
#pragma unroll
        for (int ni = 0; ni < 4; ni++) acc[mi][ni] = mfma16(af[mi], bfr[ni], acc[mi][ni]);
    }
  }
#pragma unroll
  for (int mi = 0; mi < 4; mi++) {
#pragma unroll
    for (int ni = 0; ni < 4; ni++) {
      const int gn = n0 + wc + ni * 16 + lr;
      const float bv = (mode != 0 && bias != nullptr && blockIdx.z == 0) ? bias[gn] : 0.0f;
#pragma unroll
      for (int r = 0; r < 4; r++) {
        const int gm = m0 + wr + mi * 16 + (l >> 4) * 4 + r;
        float v = acc[mi][ni][r];
        const size_t idx = zC + (size_t)gm * N + gn;
        if (mode == 0) ((u16*)Cout)[idx] = f2bf(v);
        else if (mode == 1) ((float*)Cout)[idx] = v + bv;
        else if (mode == 2) ((u16*)Cout)[idx] = f2bf(gelu_f(v + bv));
        else ((float*)Cout)[idx] =
            gelu_f(v + bv) + bf2f(((const u16*)resid)[(size_t)gm * N + gn]);
      }
    }
  }
}

// ---------------- flash attention v7 (FROZEN; K = xn; r14/r17-proven) -------
// 128 q-rows/block, 8 waves; K-only double-buffered gll16 staging (XOR-
// swizzled), V direct from L2 (chunk-tiled), vb loaded AFTER barrier 2.
// grid (S/128, H*B); writes head in-place over Qx.
__global__ __launch_bounds__(512, 2) void flash_kernel(
    const u16* __restrict__ Qx, const u16* __restrict__ Kx,
    const u16* __restrict__ xnTt, const u16* __restrict__ xn,
    u16* __restrict__ headout) {
  __shared__ u16 Ks[2][32][512];   // 64KB, K tiles, XOR-swizzled (chunk ^ row&7)
  __shared__ u16 Ps[128][40];      // 10KB
  __shared__ float fLds[128];
  __shared__ float lLds[128];

  const int tid = threadIdx.x;
  const int l = tid & 63, wv = tid >> 6;
  const int lr = l & 15, lq = l >> 4, lk8 = lq * 8;
  const int r7 = lr & 7;
  const int h = blockIdx.y >> 2, b = blockIdx.y & 3;
  const int s0 = blockIdx.x * 128;
  const size_t rowHB = (size_t)h * 8192 + (size_t)b * 2048;
  const u16* Qbase = Qx + (rowHB + s0) * 512;
  const u16* Kbase = Kx + (size_t)b * 2048 * 512;  // K = xn[b]
  const u16* Vbatch = xnTt + (size_t)b * 64 * 16384;
  const u16* xnb = xn + ((size_t)b * 2048 + s0) * 512;

  // Q fragments: wave wv owns q-rows wv*16..+16
  u16x8 q[16];
  {
    const u16* qr = Qbase + (size_t)(wv * 16 + lr) * 512 + lk8;
#pragma unroll
    for (int ks = 0; ks < 16; ks++) q[ks] = *(const u16x8*)(qr + ks * 32);
  }
  f32x4 z4 = {0.f, 0.f, 0.f, 0.f};
  f32x4 o[8][4];  // rows mi*16+lq*4+r, cols wv*64+ni*16+lr
#pragma unroll
  for (int mi = 0; mi < 8; mi++)
#pragma unroll
    for (int ni = 0; ni < 4; ni++) o[mi][ni] = z4;
  float m_r[4], l_r[4];
#pragma unroll
  for (int r = 0; r < 4; r++) { m_r[r] = -1e30f; l_r[r] = 0.f; }

  // K-only staging: 4 gll16 (1 row each) per wave, XOR-swizzled source
#define STAGE(buf, tt0)                                                      \
  do {                                                                       \
    _Pragma("unroll") for (int j = 0; j < 4; ++j) {                          \
      const int row_ = wv * 4 + j;                                           \
      gll16(Kbase + (size_t)((tt0) + row_) * 512 + ((l ^ (row_ & 7)) * 8),   \
            &Ks[buf][row_][0]);                                              \
    }                                                                        \
  } while (0)

  STAGE(0, 0);
  for (int it = 0; it < 64; ++it) {
    const int cur = it & 1;
    asm volatile("s_waitcnt vmcnt(0)" ::: "memory");
    __builtin_amdgcn_s_barrier();
    __builtin_amdgcn_sched_barrier(0);
    STAGE(cur ^ 1, (size_t)((it + 1) & 63) * 32);
    __builtin_amdgcn_sched_barrier(0);
    // ---- QK^T from Ks[cur] (swizzled chunks) ----
    f32x4 sv0 = z4, sv1 = z4;
    __builtin_amdgcn_s_setprio(1);
#pragma unroll
    for (int ks = 0; ks < 16; ks++) {
      const int col = (((ks << 2) | lq) ^ r7) << 3;
      u16x8 kb0 = *(const u16x8*)&Ks[cur][lr][col];
      u16x8 kb1 = *(const u16x8*)&Ks[cur][16 + lr][col];
      sv0 = mfma16(q[ks], kb0, sv0);
      sv1 = mfma16(q[ks], kb1, sv1);
    }
    __builtin_amdgcn_s_setprio(0);
    // ---- online softmax (wave-local rows) ----
    float tm[4], fac[4];
#pragma unroll
    for (int r = 0; r < 4; r++) tm[r] = fmaxf(sv0[r], sv1[r]);
#pragma unroll
    for (int r = 0; r < 4; r++) {
      tm[r] = fmaxf(tm[r], __shfl_xor(tm[r], 1));
      tm[r] = fmaxf(tm[r], __shfl_xor(tm[r], 2));
      tm[r] = fmaxf(tm[r], __shfl_xor(tm[r], 4));
      tm[r] = fmaxf(tm[r], __shfl_xor(tm[r], 8));
    }
#pragma unroll
    for (int r = 0; r < 4; r++) {
      float mn = fmaxf(m_r[r], tm[r]);
      fac[r] = __expf(m_r[r] - mn);
      m_r[r] = mn;
      float p0 = __expf(sv0[r] - mn);
      float p1 = __expf(sv1[r] - mn);
      const int prow = wv * 16 + lq * 4 + r;
      Ps[prow][lr] = f2bf(p0);
      Ps[prow][16 + lr] = f2bf(p1);
      float rs = p0 + p1;
      rs += __shfl_xor(rs, 1);
      rs += __shfl_xor(rs, 2);
      rs += __shfl_xor(rs, 4);
      rs += __shfl_xor(rs, 8);
      l_r[r] = l_r[r] * fac[r] + rs;
    }
    if (lr == 0) {
#pragma unroll
      for (int r = 0; r < 4; r++) fLds[wv * 16 + lq * 4 + r] = fac[r];
    }
    asm volatile("s_waitcnt lgkmcnt(0)" ::: "memory");
    __builtin_amdgcn_s_barrier();
    __builtin_amdgcn_sched_barrier(0);
    // ---- V fragments direct from global (L2-resident) ----
    const u16* Vt_ = Vbatch + (size_t)it * 16384;
    u16x8 vb[4];
#pragma unroll
    for (int ni = 0; ni < 4; ni++)
      vb[ni] = *(const u16x8*)(Vt_ + lq * 4096 + (size_t)(wv * 64 + ni * 16 + lr) * 8);
    __builtin_amdgcn_sched_barrier(0);
    // ---- rescale o (hides part of the V latency) ----
#pragma unroll
    for (int mi = 0; mi < 8; mi++) {
#pragma unroll
      for (int r = 0; r < 4; r++) {
        const float fv = fLds[mi * 16 + lq * 4 + r];
#pragma unroll
        for (int ni = 0; ni < 4; ni++) o[mi][ni][r] *= fv;
      }
    }
    // wait vb (4 newest); leave the 4 next-tile K stages in flight
    asm volatile("s_waitcnt vmcnt(4)" ::: "memory");
    __builtin_amdgcn_sched_barrier(0);
    // ---- PV ----
    __builtin_amdgcn_s_setprio(1);
#pragma unroll
    for (int mi = 0; mi < 8; mi++) {
      u16x8 pa = *(const u16x8*)&Ps[mi * 16 + lr][lk8];
#pragma unroll
      for (int ni = 0; ni < 4; ni++) o[mi][ni] = mfma16(pa, vb[ni], o[mi][ni]);
    }
    __builtin_amdgcn_s_setprio(0);
  }
#undef STAGE
  // drain in-flight global_load_lds before LDS teardown
  asm volatile("s_waitcnt vmcnt(0)" ::: "memory");
  if (lr == 0) {
#pragma unroll
    for (int r = 0; r < 4; r++) lLds[wv * 16 + lq * 4 + r] = l_r[r];
  }
  __syncthreads();
  u16* outp = headout + (rowHB + s0) * 512;
#pragma unroll
  for (int mi = 0; mi < 8; mi++) {
#pragma unroll
    for (int r = 0; r < 4; r++) {
      const int row = mi * 16 + lq * 4 + r;
      const float linv = 1.0f / lLds[row];
      const u16* xr = xnb + (size_t)row * 512;
      u16* orow = outp + (size_t)row * 512;
#pragma unroll
      for (int ni = 0; ni < 4; ni++) {
        const int c = wv * 64 + ni * 16 + lr;
        orow[c] = f2bf(o[mi][ni][r] * linv + bf2f(xr[c]));
      }
    }
  }
}

extern "C" void kernel_launch(void* const* d_in, const int* in_sizes, int n_in,
                              void* d_out, int out_size, void* d_ws, size_t ws_size,
                              hipStream_t stream) {
  (void)in_sizes; (void)n_in; (void)out_size; (void)ws_size;
  const float* x   = (const float*)d_in[0];
  const float* Qw  = (const float*)d_in[1];
  const float* Kw  = (const float*)d_in[2];
  const float* g1  = (const float*)d_in[3];
  const float* be1 = (const float*)d_in[4];
  const float* Wp  = (const float*)d_in[5];
  const float* bp  = (const float*)d_in[6];
  const float* g2  = (const float*)d_in[7];
  const float* be2 = (const float*)d_in[8];
  const float* W1  = (const float*)d_in[9];
  const float* b1  = (const float*)d_in[10];
  const float* W2  = (const float*)d_in[11];
  const float* b2  = (const float*)d_in[12];
  float* out = (float*)d_out;

  // workspace carve (elements of u16)
  u16* ws = (u16*)d_ws;
  size_t off = 0;
  u16* Qc   = ws + off; off += 8ull * 512 * 512;     // Q bf16 [h][d][e], scaled
  u16* Kc   = ws + off; off += 8ull * 512 * 512;     // K bf16 [h][d][e]
  u16* Mht  = ws + off; off += 8ull * 512 * 512;     // (QK^T)^T per head [h][d'][d]
  u16* Wpt  = ws + off; off += 512ull * 4096;        // [e][hd]
  u16* W1t  = ws + off; off += 2048ull * 512;        // [n][d]
  u16* W2t  = ws + off; off += 512ull * 2048;        // [e][k]
  u16* xnb  = ws + off; off += 8192ull * 512;        // LN1 out bf16 (also K for flash)
  u16* xnTt = ws + off; off += 4ull * 512 * 2048;    // V tiled [b][64][4][512][8]
  u16* Qx   = ws + off; off += 8ull * 8192 * 512;    // Qx' = xn*Mht; becomes head in-place
  u16* yn   = ws + off; off += 8192ull * 512;        // LN2 out bf16 (also MLP2 resid)
  float* y   = (float*)(ws + off); off += 8192ull * 512 * 4;  // proj fp32, 2 split-K partials
  u16* h1 = Qx;  // alias: head dead after proj GEMM

  const float qscale = 0.04419417382415922f;  // 1/sqrt(512)
  // unified weight prep (5 launches -> 1)
  prep_kernel<<<8192, 256, 0, stream>>>(Qw, Kw, Wp, W1, W2, Qc, Kc, Wpt, W1t, W2t, qscale);
  // LN1 with fused V pre-tiling (row-major xnb + chunk-major xnTt)
  ln_kernel<<<8192, 256, 0, stream>>>(x, nullptr, g1, be1, xnb, xnTt);
  // Mht[h][d'][d] = sum_e K[h][d'][e] * Q[h][d][e]   (tiny, 2.1 GF)
  gemm_kernel<<<dim3(4, 4, 8), 256, 0, stream>>>(Kc, Qc, nullptr, nullptr, Mht,
      512, 512, 512, 512, 0, 262144, 262144, 262144, 0);
  // Qx' = xn * Mht  (replaces BOTH Q and K projections)
  gemm_kernel<<<dim3(4, 64, 8), 256, 0, stream>>>(xnb, Mht, nullptr, nullptr, Qx,
      8192, 512, 512, 512, 0, 0, 262144, 4194304, 0);
  // flash attention: K = xn (L2-resident), head overwrites Qx
  flash_kernel<<<dim3(16, 32), 512, 0, stream>>>(Qx, xnb, xnTt, xnb, Qx);
  // projection: y = head_cat @ Wp + bp, split-K x2 over Wpt's 4096-wide rows
  gemm_kernel<<<dim3(4, 64, 2), 256, 0, stream>>>(Qx, Wpt, bp, nullptr, y,
      8192, 512, 2048, 4096, 1, 16777216, 2048, 4194304, 4194304);
  // LN2 (sums the two split-K partials); bf16 out only
  ln_kernel<<<8192, 256, 0, stream>>>(y, y + 4194304, g2, be2, yn, nullptr);
  // MLP
  gemm_kernel<<<dim3(16, 64, 1), 256, 0, stream>>>(yn, W1t, b1, nullptr, h1,
      8192, 2048, 512, 512, 2, 0, 0, 0, 0);
  gemm_kernel<<<dim3(4, 64, 1), 256, 0, stream>>>(h1, W2t, b2, yn, out,
      8192, 512, 2048, 2048, 4, 0, 0, 0, 0);
}

// Round 20
// 854.321 us; speedup vs baseline: 1.0116x; 1.0116x over previous
//
#include <hip/hip_runtime.h>

using u16 = unsigned short;
typedef u16 u16x8 __attribute__((ext_vector_type(8)));
typedef __bf16 bf16x8 __attribute__((ext_vector_type(8)));
typedef float f32x4 __attribute__((ext_vector_type(4)));

__device__ __forceinline__ u16 f2bf(float f) {
  unsigned u = __builtin_bit_cast(unsigned, f);
  u += 0x7fffu + ((u >> 16) & 1u);
  return (u16)(u >> 16);
}
__device__ __forceinline__ float bf2f(u16 h) {
  unsigned u = ((unsigned)h) << 16;
  return __builtin_bit_cast(float, u);
}
__device__ __forceinline__ f32x4 mfma16(u16x8 a, u16x8 b, f32x4 c) {
  return __builtin_amdgcn_mfma_f32_16x16x32_bf16(
      __builtin_bit_cast(bf16x8, a), __builtin_bit_cast(bf16x8, b), c, 0, 0, 0);
}
__device__ __forceinline__ float gelu_f(float v) {
  return 0.5f * v * (1.0f + erff(v * 0.70710678118654752f));
}
// async global->LDS, 16B per lane; lds dest = base + lane*16 (wave-uniform base)
__device__ __forceinline__ void gll16(const u16* g, u16* l) {
  __builtin_amdgcn_global_load_lds(
      (const __attribute__((address_space(1))) unsigned*)g,
      (__attribute__((address_space(3))) unsigned*)l, 16, 0, 0);
}

// ---------------- unified weight prep: casts + transposes in ONE launch -----
__global__ __launch_bounds__(256) void prep_kernel(
    const float* __restrict__ Qw, const float* __restrict__ Kw,
    const float* __restrict__ Wp, const float* __restrict__ W1,
    const float* __restrict__ W2, u16* __restrict__ Qc, u16* __restrict__ Kc,
    u16* __restrict__ Wpt, u16* __restrict__ W1t, u16* __restrict__ W2t,
    float qscale) {
  const int bid = blockIdx.x;
  const int tid = threadIdx.x;
  if (bid < 4096) {  // flat vectorized casts
    const float* in = (bid < 2048) ? Qw : Kw;
    u16* outp = (bid < 2048) ? Qc : Kc;
    const float sc = (bid < 2048) ? qscale : 1.0f;
    const size_t i = ((size_t)(bid & 2047) * 256 + tid) * 4;
    float4 v = *(const float4*)(in + i);
    outp[i] = f2bf(v.x * sc);
    outp[i + 1] = f2bf(v.y * sc);
    outp[i + 2] = f2bf(v.z * sc);
    outp[i + 3] = f2bf(v.w * sc);
    return;
  }
  __shared__ float tile[32][33];
  const float* in;
  u16* outp;
  int R, C, t;
  if (bid < 6144)      { in = Wp; outp = Wpt; R = 4096; C = 512;  t = bid - 4096; }
  else if (bid < 7168) { in = W1; outp = W1t; R = 512;  C = 2048; t = bid - 6144; }
  else                 { in = W2; outp = W2t; R = 2048; C = 512;  t = bid - 7168; }
  const int tilesX = C >> 5;
  const int cx = (t % tilesX) * 32, ry = (t / tilesX) * 32;
  const int tx = tid & 31, ty = tid >> 5;
#pragma unroll
  for (int i = 0; i < 32; i += 8)
    tile[ty + i][tx] = in[(size_t)(ry + ty + i) * C + (cx + tx)];
  __syncthreads();
#pragma unroll
  for (int i = 0; i < 32; i += 8)
    outp[(size_t)(cx + ty + i) * R + (ry + tx)] = f2bf(tile[tx][ty + i]);
}

// V pre-tiling, chunk-major: xnb [b][2048][512] -> out [b][64][4][512][8]
__global__ void vtile_kernel(const u16* __restrict__ in, u16* __restrict__ out) {
  __shared__ u16 tile[32][33];
  const int b = blockIdx.z;
  const int d0 = blockIdx.x * 32, t0 = blockIdx.y * 32;
  const int tx = threadIdx.x, ty = threadIdx.y;
  const u16* ip = in + (size_t)b * 2048 * 512;
#pragma unroll
  for (int i = 0; i < 32; i += 8)
    tile[ty + i][tx] = ip[(size_t)(t0 + ty + i) * 512 + d0 + tx];
  __syncthreads();
  u16* op = out + ((size_t)b * 64 + (t0 >> 5)) * 16384;
#pragma unroll
  for (int i = 0; i < 32; i += 8) {
    const int d = d0 + ty + i;
    op[(size_t)(tx >> 3) * 4096 + (size_t)d * 8 + (tx & 7)] = tile[tx][ty + i];
  }
}

// ---------------- layernorm (D=512); optional second input (split-K sum) ----
__global__ __launch_bounds__(256) void ln_kernel(
    const float* __restrict__ x, const float* __restrict__ x2,
    const float* __restrict__ g, const float* __restrict__ b,
    u16* __restrict__ obf, float* __restrict__ of32) {
  const int D = 512;
  int row = blockIdx.x;
  const float* xr = x + (size_t)row * D;
  float2 v = ((const float2*)xr)[threadIdx.x];
  if (x2 != nullptr) {
    float2 v2 = ((const float2*)(x2 + (size_t)row * D))[threadIdx.x];
    v.x += v2.x;
    v.y += v2.y;
  }
  float s = v.x + v.y;
#pragma unroll
  for (int o = 1; o < 64; o <<= 1) s += __shfl_xor(s, o);
  __shared__ float red[4];
  int wid = threadIdx.x >> 6;
  if ((threadIdx.x & 63) == 0) red[wid] = s;
  __syncthreads();
  float mean = (red[0] + red[1] + red[2] + red[3]) * (1.0f / D);
  float dx = v.x - mean, dy = v.y - mean;
  float q = dx * dx + dy * dy;
#pragma unroll
  for (int o = 1; o < 64; o <<= 1) q += __shfl_xor(q, o);
  __syncthreads();
  if ((threadIdx.x & 63) == 0) red[wid] = q;
  __syncthreads();
  float var = (red[0] + red[1] + red[2] + red[3]) * (1.0f / D);
  float rstd = rsqrtf(var + 1e-6f);
  int c = threadIdx.x * 2;
  float o0 = dx * rstd * g[c] + b[c];
  float o1 = dy * rstd * g[c + 1] + b[c + 1];
  obf[(size_t)row * D + c] = f2bf(o0);
  obf[(size_t)row * D + c + 1] = f2bf(o1);
  if (of32 != nullptr) {
    of32[(size_t)row * D + c] = o0;
    of32[(size_t)row * D + c + 1] = o1;
  }
}

// ---------------- bf16 GEMM v3: C[M,N] = A[M,K] * Bt[N,K]^T ------------------
// m97 pattern: global_load_lds width-16 staging, BK=64, both-sides XOR swizzle.
// ldB = physical row stride of Bt. bias applied only on z==0.
// mode 0: bf16 out           mode 1: fp32 out, +bias
// mode 2: bf16 out, gelu(+bias)   mode 4: fp32 out, gelu(+bias)+bf16-resid
__global__ __launch_bounds__(256) void gemm_kernel(
    const u16* __restrict__ A, const u16* __restrict__ Bt,
    const float* __restrict__ bias, const void* __restrict__ resid,
    void* __restrict__ Cout, int M, int N, int K, int ldB, int mode,
    size_t sA, size_t sB, size_t sC, size_t aHS) {
  __shared__ u16 As[128 * 64];
  __shared__ u16 Bs[128 * 64];
  A += (size_t)blockIdx.z * sA;
  Bt += (size_t)blockIdx.z * sB;
  const size_t zC = (size_t)blockIdx.z * sC;
  const int m0 = blockIdx.y * 128, n0 = blockIdx.x * 128;
  const int tid = threadIdx.x;
  const int l = tid & 63, wv = tid >> 6;
  const int wr = (wv >> 1) * 64, wc = (wv & 1) * 64;
  const int lr = l & 15, lq = l >> 4;
  const int srow = l >> 3;   // row-in-group 0..7
  const int sc = l & 7;      // chunk 0..7
  f32x4 z4 = {0.f, 0.f, 0.f, 0.f};
  f32x4 acc[4][4];
#pragma unroll
  for (int mi = 0; mi < 4; mi++)
#pragma unroll
    for (int ni = 0; ni < 4; ni++) acc[mi][ni] = z4;

  for (int k0 = 0; k0 < K; k0 += 64) {
    __syncthreads();
#pragma unroll
    for (int j = 0; j < 4; ++j) {
      const int r = wv * 32 + j * 8 + srow;
      const int kc = (sc ^ (r & 7)) * 8;  // pre-swizzled source chunk
      const u16* asrc;
      if (aHS) asrc = A + (size_t)(k0 >> 9) * aHS + (size_t)(m0 + r) * 512 + ((k0 & 511) + kc);
      else asrc = A + (size_t)(m0 + r) * K + k0 + kc;
      gll16(asrc, &As[(wv * 32 + j * 8) * 64]);
      const u16* bsrc = Bt + (size_t)(n0 + r) * ldB + k0 + kc;
      gll16(bsrc, &Bs[(wv * 32 + j * 8) * 64]);
    }
    asm volatile("s_waitcnt vmcnt(0)" ::: "memory");
    __syncthreads();
#pragma unroll
    for (int kk = 0; kk < 2; ++kk) {
      const int rc = ((kk * 4 + lq) ^ (lr & 7)) * 8;  // swizzled read chunk
      u16x8 af[4], bfr[4];
#pragma unroll
      for (int mi = 0; mi < 4; mi++) af[mi] = *(const u16x8*)&As[(wr + mi * 16 + lr) * 64 + rc];
#pragma unroll
      for (int ni = 0; ni < 4; ni++) bfr[ni] = *(const u16x8*)&Bs[(wc + ni * 16 + lr) * 64 + rc];
#pragma unroll
      for (int mi = 0; mi < 4; mi++)
#pragma unroll
        for (int ni = 0; ni < 4; ni++) acc[mi][ni] = mfma16(af[mi], bfr[ni], acc[mi][ni]);
    }
  }
#pragma unroll
  for (int mi = 0; mi < 4; mi++) {
#pragma unroll
    for (int ni = 0; ni < 4; ni++) {
      const int gn = n0 + wc + ni * 16 + lr;
      const float bv = (mode != 0 && bias != nullptr && blockIdx.z == 0) ? bias[gn] : 0.0f;
#pragma unroll
      for (int r = 0; r < 4; r++) {
        const int gm = m0 + wr + mi * 16 + (l >> 4) * 4 + r;
        float v = acc[mi][ni][r];
        const size_t idx = zC + (size_t)gm * N + gn;
        if (mode == 0) ((u16*)Cout)[idx] = f2bf(v);
        else if (mode == 1) ((float*)Cout)[idx] = v + bv;
        else if (mode == 2) ((u16*)Cout)[idx] = f2bf(gelu_f(v + bv));
        else ((float*)Cout)[idx] =
            gelu_f(v + bv) + bf2f(((const u16*)resid)[(size_t)gm * N + gn]);
      }
    }
  }
}

// ---------------- flash attention v7 (FROZEN; K = xn; r14/r17-proven) -------
// 128 q-rows/block, 8 waves; K-only double-buffered gll16 staging (XOR-
// swizzled), V direct from L2 (chunk-tiled), vb loaded AFTER barrier 2.
// grid (S/128, H*B); writes head in-place over Qx.
__global__ __launch_bounds__(512, 2) void flash_kernel(
    const u16* __restrict__ Qx, const u16* __restrict__ Kx,
    const u16* __restrict__ xnTt, const u16* __restrict__ xn,
    u16* __restrict__ headout) {
  __shared__ u16 Ks[2][32][512];   // 64KB, K tiles, XOR-swizzled (chunk ^ row&7)
  __shared__ u16 Ps[128][40];      // 10KB
  __shared__ float fLds[128];
  __shared__ float lLds[128];

  const int tid = threadIdx.x;
  const int l = tid & 63, wv = tid >> 6;
  const int lr = l & 15, lq = l >> 4, lk8 = lq * 8;
  const int r7 = lr & 7;
  const int h = blockIdx.y >> 2, b = blockIdx.y & 3;
  const int s0 = blockIdx.x * 128;
  const size_t rowHB = (size_t)h * 8192 + (size_t)b * 2048;
  const u16* Qbase = Qx + (rowHB + s0) * 512;
  const u16* Kbase = Kx + (size_t)b * 2048 * 512;  // K = xn[b]
  const u16* Vbatch = xnTt + (size_t)b * 64 * 16384;
  const u16* xnb = xn + ((size_t)b * 2048 + s0) * 512;

  // Q fragments: wave wv owns q-rows wv*16..+16
  u16x8 q[16];
  {
    const u16* qr = Qbase + (size_t)(wv * 16 + lr) * 512 + lk8;
#pragma unroll
    for (int ks = 0; ks < 16; ks++) q[ks] = *(const u16x8*)(qr + ks * 32);
  }
  f32x4 z4 = {0.f, 0.f, 0.f, 0.f};
  f32x4 o[8][4];  // rows mi*16+lq*4+r, cols wv*64+ni*16+lr
#pragma unroll
  for (int mi = 0; mi < 8; mi++)
#pragma unroll
    for (int ni = 0; ni < 4; ni++) o[mi][ni] = z4;
  float m_r[4], l_r[4];
#pragma unroll
  for (int r = 0; r < 4; r++) { m_r[r] = -1e30f; l_r[r] = 0.f; }

  // K-only staging: 4 gll16 (1 row each) per wave, XOR-swizzled source
#define STAGE(buf, tt0)                                                      \
  do {                                                                       \
    _Pragma("unroll") for (int j = 0; j < 4; ++j) {                          \
      const int row_ = wv * 4 + j;                                           \
      gll16(Kbase + (size_t)((tt0) + row_) * 512 + ((l ^ (row_ & 7)) * 8),   \
            &Ks[buf][row_][0]);                                              \
    }                                                                        \
  } while (0)

  STAGE(0, 0);
  for (int it = 0; it < 64; ++it) {
    const int cur = it & 1;
    asm volatile("s_waitcnt vmcnt(0)" ::: "memory");
    __builtin_amdgcn_s_barrier();
    __builtin_amdgcn_sched_barrier(0);
    STAGE(cur ^ 1, (size_t)((it + 1) & 63) * 32);
    __builtin_amdgcn_sched_barrier(0);
    // ---- QK^T from Ks[cur] (swizzled chunks) ----
    f32x4 sv0 = z4, sv1 = z4;
    __builtin_amdgcn_s_setprio(1);
#pragma unroll
    for (int ks = 0; ks < 16; ks++) {
      const int col = (((ks << 2) | lq) ^ r7) << 3;
      u16x8 kb0 = *(const u16x8*)&Ks[cur][lr][col];
      u16x8 kb1 = *(const u16x8*)&Ks[cur][16 + lr][col];
      sv0 = mfma16(q[ks], kb0, sv0);
      sv1 = mfma16(q[ks], kb1, sv1);
    }
    __builtin_amdgcn_s_setprio(0);
    // ---- online softmax (wave-local rows) ----
    float tm[4], fac[4];
#pragma unroll
    for (int r = 0; r < 4; r++) tm[r] = fmaxf(sv0[r], sv1[r]);
#pragma unroll
    for (int r = 0; r < 4; r++) {
      tm[r] = fmaxf(tm[r], __shfl_xor(tm[r], 1));
      tm[r] = fmaxf(tm[r], __shfl_xor(tm[r], 2));
      tm[r] = fmaxf(tm[r], __shfl_xor(tm[r], 4));
      tm[r] = fmaxf(tm[r], __shfl_xor(tm[r], 8));
    }
#pragma unroll
    for (int r = 0; r < 4; r++) {
      float mn = fmaxf(m_r[r], tm[r]);
      fac[r] = __expf(m_r[r] - mn);
      m_r[r] = mn;
      float p0 = __expf(sv0[r] - mn);
      float p1 = __expf(sv1[r] - mn);
      const int prow = wv * 16 + lq * 4 + r;
      Ps[prow][lr] = f2bf(p0);
      Ps[prow][16 + lr] = f2bf(p1);
      float rs = p0 + p1;
      rs += __shfl_xor(rs, 1);
      rs += __shfl_xor(rs, 2);
      rs += __shfl_xor(rs, 4);
      rs += __shfl_xor(rs, 8);
      l_r[r] = l_r[r] * fac[r] + rs;
    }
    if (lr == 0) {
#pragma unroll
      for (int r = 0; r < 4; r++) fLds[wv * 16 + lq * 4 + r] = fac[r];
    }
    asm volatile("s_waitcnt lgkmcnt(0)" ::: "memory");
    __builtin_amdgcn_s_barrier();
    __builtin_amdgcn_sched_barrier(0);
    // ---- V fragments direct from global (L2-resident) ----
    const u16* Vt_ = Vbatch + (size_t)it * 16384;
    u16x8 vb[4];
#pragma unroll
    for (int ni = 0; ni < 4; ni++)
      vb[ni] = *(const u16x8*)(Vt_ + lq * 4096 + (size_t)(wv * 64 + ni * 16 + lr) * 8);
    __builtin_amdgcn_sched_barrier(0);
    // ---- rescale o (hides part of the V latency) ----
#pragma unroll
    for (int mi = 0; mi < 8; mi++) {
#pragma unroll
      for (int r = 0; r < 4; r++) {
        const float fv = fLds[mi * 16 + lq * 4 + r];
#pragma unroll
        for (int ni = 0; ni < 4; ni++) o[mi][ni][r] *= fv;
      }
    }
    // wait vb (4 newest); leave the 4 next-tile K stages in flight
    asm volatile("s_waitcnt vmcnt(4)" ::: "memory");
    __builtin_amdgcn_sched_barrier(0);
    // ---- PV ----
    __builtin_amdgcn_s_setprio(1);
#pragma unroll
    for (int mi = 0; mi < 8; mi++) {
      u16x8 pa = *(const u16x8*)&Ps[mi * 16 + lr][lk8];
#pragma unroll
      for (int ni = 0; ni < 4; ni++) o[mi][ni] = mfma16(pa, vb[ni], o[mi][ni]);
    }
    __builtin_amdgcn_s_setprio(0);
  }
#undef STAGE
  // drain in-flight global_load_lds before LDS teardown
  asm volatile("s_waitcnt vmcnt(0)" ::: "memory");
  if (lr == 0) {
#pragma unroll
    for (int r = 0; r < 4; r++) lLds[wv * 16 + lq * 4 + r] = l_r[r];
  }
  __syncthreads();
  u16* outp = headout + (rowHB + s0) * 512;
#pragma unroll
  for (int mi = 0; mi < 8; mi++) {
#pragma unroll
    for (int r = 0; r < 4; r++) {
      const int row = mi * 16 + lq * 4 + r;
      const float linv = 1.0f / lLds[row];
      const u16* xr = xnb + (size_t)row * 512;
      u16* orow = outp + (size_t)row * 512;
#pragma unroll
      for (int ni = 0; ni < 4; ni++) {
        const int c = wv * 64 + ni * 16 + lr;
        orow[c] = f2bf(o[mi][ni][r] * linv + bf2f(xr[c]));
      }
    }
  }
}

extern "C" void kernel_launch(void* const* d_in, const int* in_sizes, int n_in,
                              void* d_out, int out_size, void* d_ws, size_t ws_size,
                              hipStream_t stream) {
  (void)in_sizes; (void)n_in; (void)out_size; (void)ws_size;
  const float* x   = (const float*)d_in[0];
  const float* Qw  = (const float*)d_in[1];
  const float* Kw  = (const float*)d_in[2];
  const float* g1  = (const float*)d_in[3];
  const float* be1 = (const float*)d_in[4];
  const float* Wp  = (const float*)d_in[5];
  const float* bp  = (const float*)d_in[6];
  const float* g2  = (const float*)d_in[7];
  const float* be2 = (const float*)d_in[8];
  const float* W1  = (const float*)d_in[9];
  const float* b1  = (const float*)d_in[10];
  const float* W2  = (const float*)d_in[11];
  const float* b2  = (const float*)d_in[12];
  float* out = (float*)d_out;

  // workspace carve (elements of u16)
  u16* ws = (u16*)d_ws;
  size_t off = 0;
  u16* Qc   = ws + off; off += 8ull * 512 * 512;     // Q bf16 [h][d][e], scaled
  u16* Kc   = ws + off; off += 8ull * 512 * 512;     // K bf16 [h][d][e]
  u16* Mht  = ws + off; off += 8ull * 512 * 512;     // (QK^T)^T per head [h][d'][d]
  u16* Wpt  = ws + off; off += 512ull * 4096;        // [e][hd]
  u16* W1t  = ws + off; off += 2048ull * 512;        // [n][d]
  u16* W2t  = ws + off; off += 512ull * 2048;        // [e][k]
  u16* xnb  = ws + off; off += 8192ull * 512;        // LN1 out bf16 (also K for flash)
  u16* xnTt = ws + off; off += 4ull * 512 * 2048;    // V tiled [b][64][4][512][8]
  u16* Qx   = ws + off; off += 8ull * 8192 * 512;    // Qx' = xn*Mht; becomes head in-place
  u16* yn   = ws + off; off += 8192ull * 512;        // LN2 out bf16 (also MLP2 resid)
  float* y   = (float*)(ws + off); off += 8192ull * 512 * 4;  // proj fp32, 2 split-K partials
  u16* h1 = Qx;  // alias: head dead after proj GEMM

  const float qscale = 0.04419417382415922f;  // 1/sqrt(512)
  // unified weight prep (5 launches -> 1)
  prep_kernel<<<8192, 256, 0, stream>>>(Qw, Kw, Wp, W1, W2, Qc, Kc, Wpt, W1t, W2t, qscale);
  // LN1 and V pre-tiling
  ln_kernel<<<8192, 256, 0, stream>>>(x, nullptr, g1, be1, xnb, nullptr);
  vtile_kernel<<<dim3(16, 64, 4), dim3(32, 8), 0, stream>>>(xnb, xnTt);
  // Mht[h][d'][d] = sum_e K[h][d'][e] * Q[h][d][e]   (tiny, 2.1 GF)
  gemm_kernel<<<dim3(4, 4, 8), 256, 0, stream>>>(Kc, Qc, nullptr, nullptr, Mht,
      512, 512, 512, 512, 0, 262144, 262144, 262144, 0);
  // Qx' = xn * Mht  (replaces BOTH Q and K projections)
  gemm_kernel<<<dim3(4, 64, 8), 256, 0, stream>>>(xnb, Mht, nullptr, nullptr, Qx,
      8192, 512, 512, 512, 0, 0, 262144, 4194304, 0);
  // flash attention: K = xn (L2-resident), head overwrites Qx
  flash_kernel<<<dim3(16, 32), 512, 0, stream>>>(Qx, xnb, xnTt, xnb, Qx);
  // projection: y = head_cat @ Wp + bp, split-K x2 over Wpt's 4096-wide rows
  gemm_kernel<<<dim3(4, 64, 2), 256, 0, stream>>>(Qx, Wpt, bp, nullptr, y,
      8192, 512, 2048, 4096, 1, 16777216, 2048, 4194304, 4194304);
  // LN2 (sums the two split-K partials); bf16 out only
  ln_kernel<<<8192, 256, 0, stream>>>(y, y + 4194304, g2, be2, yn, nullptr);
  // MLP
  gemm_kernel<<<dim3(16, 64, 1), 256, 0, stream>>>(yn, W1t, b1, nullptr, h1,
      8192, 2048, 512, 512, 2, 0, 0, 0, 0);
  gemm_kernel<<<dim3(4, 64, 1), 256, 0, stream>>>(h1, W2t, b2, yn, out,
      8192, 512, 2048, 2048, 4, 0, 0, 0, 0);
}